// Round 2
// baseline (107.444 us; speedup 1.0000x reference)
//
#include <hip/hip_runtime.h>
#include <math.h>

#define NROWS 8192
#define DDIM  128
#define K20   28.853900817779268f        // 20 * log2(e)
#define K2    (K20 * K20)                // 832.5476
#define DTHR  8.3255f                    // 0.01 * K2 : diagonal mask (real pairs >= ~750)
#define NBLK  4160                       // sum_{I=0}^{63} (128 - 2I) triangular blocks

typedef _Float16 f16x8 __attribute__((ext_vector_type(8)));
typedef _Float16 f16x4 __attribute__((ext_vector_type(4)));
typedef _Float16 f16x2 __attribute__((ext_vector_type(2)));
typedef float    f32x4 __attribute__((ext_vector_type(4)));

#ifndef __has_builtin
#define __has_builtin(x) 0
#endif
#if __has_builtin(__builtin_amdgcn_fdot2)
#define HAVE_FDOT2 1
#else
#define HAVE_FDOT2 0
#endif

// Fragment-major layout for mfma_f32_16x16x32_f16 (16-row groups):
//   xf[g*2048 + kk*512 + l*8 + j] = x[i = g*16 + (l&15)][k = kk*32 + (l>>4)*8 + j]
//
// ws layout (after xf):
//   rowL[128][8192], rowS[128][8192]  : row-sum partials, slot = col-block Jc
//   colL[ 64][8192], colS[ 64][8192]  : mirrored col-sum partials, slot = row-block I
// Every slot finalize reads is written by exactly one wave (no atomics, no zeroing):
//   row i (I = i>>7):  sum_{Jc=2I}^{127} rowX[Jc][i] + sum_{b=0}^{I-1} colX[b][i]

// ---- fp32 -> f16 frag-major transform + zero out ----
__global__ void convert_kernel(const float* __restrict__ x,
                               _Float16* __restrict__ xf,
                               float* __restrict__ out) {
    int idx = (blockIdx.x * 256 + threadIdx.x) * 4;    // flat (i,k) element index
    float4 v = *(const float4*)(x + idx);
    f16x4 h = { (_Float16)v.x, (_Float16)v.y, (_Float16)v.z, (_Float16)v.w };
    const int i = idx >> 7, k = idx & 127;             // k multiple of 4
    const int lane = (((k >> 3) & 3) << 4) | (i & 15);
    const int dst = (i >> 4) * 2048 + (k >> 5) * 512 + lane * 8 + (k & 7);
    *(f16x4*)(xf + dst) = h;
    if (blockIdx.x == 0 && threadIdx.x == 0) out[0] = 0.0f;
}

// ---- main pair kernel, symmetric (upper-triangle) version.
//      Block = 128 rows x 64 cols, 4 waves (wave = 32 rows, two 16-row A frags).
//      Triangular grid: block t -> (I, Jc) with Jc >= 2I.  Jc in {2I, 2I+1} are
//      the diagonal blocks (computed fully, both pair orders, no mirror);
//      Jc >= 2I+2 blocks are strictly above the diagonal square and mirror
//      their column sums (d and the MFMA dot are exactly symmetric).
//      B tiles register-double-buffered; all partial sums stored non-atomically
//      to unique slots. ----
__global__ __launch_bounds__(256, 4) void pair_kernel(
        const _Float16* __restrict__ xf,
        float* __restrict__ rowL, float* __restrict__ rowS,
        float* __restrict__ colL, float* __restrict__ colS) {
    __shared__ float shcL[64], shcS[64];

    // decode triangular block index: base(I) = I*(129-I)
    const int t = blockIdx.x;
    int I = (int)((129.0f - sqrtf(16641.0f - 4.0f * (float)t)) * 0.5f);
    while (I * (129 - I) > t) --I;
    while ((I + 1) * (128 - I) <= t) ++I;
    const int Jc = 2 * I + (t - I * (129 - I));
    const bool mirror = (Jc >= 2 * I + 2);

    const int w = threadIdx.x >> 6;
    const int lane = threadIdx.x & 63;
    const int i0 = I * 128 + w * 32;

    if (mirror) {
        if (threadIdx.x < 64) { shcL[threadIdx.x] = 0.f; shcS[threadIdx.x] = 0.f; }
        __syncthreads();
    }

    // A fragments resident: 2 strips x 4 k-chunks, one 1 KB coalesced load each
    const _Float16* ab = xf + (size_t)(I * 8 + w * 2) * 2048 + lane * 8;
    f16x8 a0[4], a1[4];
    #pragma unroll
    for (int kk = 0; kk < 4; ++kk) {
        a0[kk] = *(const f16x8*)(ab + kk * 512);
        a1[kk] = *(const f16x8*)(ab + 2048 + kk * 512);
    }

    float nL[8], nS[8];
    #pragma unroll
    for (int r = 0; r < 8; ++r) { nL[r] = 0.f; nS[r] = 0.f; }

    const _Float16* bb = xf + (size_t)(Jc * 4) * 2048 + lane * 8;

    f16x8 b0[4], b1[4];
    #pragma unroll
    for (int kk = 0; kk < 4; ++kk) b0[kk] = *(const f16x8*)(bb + kk * 512);

    // per-tile compute: 8 MFMA + epilogue + (mirror) col reduce into LDS
    auto compute = [&](f16x8 (&b)[4], int g) {
        f32x4 acc0 = {0.f,0.f,0.f,0.f}, acc1 = {0.f,0.f,0.f,0.f};
        #pragma unroll
        for (int kk = 0; kk < 4; ++kk) {
            acc0 = __builtin_amdgcn_mfma_f32_16x16x32_f16(a0[kk], b[kk], acc0, 0, 0, 0);
            acc1 = __builtin_amdgcn_mfma_f32_16x16x32_f16(a1[kk], b[kk], acc1, 0, 0, 0);
        }
        float cs = 0.f, cl = 0.f;
        #pragma unroll
        for (int r = 0; r < 4; ++r) {
            float d2s = fmaf(-2.0f * K2, acc0[r], 2.0f * K2);    // (20*log2e)^2 * d^2
            float ds  = __builtin_amdgcn_sqrtf(d2s);             // NaN on diag, masked below
            float tt  = __builtin_amdgcn_exp2f(-ds);             // exp(-20 d)
            tt = (d2s < DTHR) ? 0.0f : tt;                       // exact diagonal exclusion
            nS[r] += tt; cs += tt;
            nL[r] = fmaf(tt, tt, nL[r]); cl = fmaf(tt, tt, cl);
        }
        #pragma unroll
        for (int r = 0; r < 4; ++r) {
            float d2s = fmaf(-2.0f * K2, acc1[r], 2.0f * K2);
            float ds  = __builtin_amdgcn_sqrtf(d2s);
            float tt  = __builtin_amdgcn_exp2f(-ds);
            tt = (d2s < DTHR) ? 0.0f : tt;
            nS[4 + r] += tt; cs += tt;
            nL[4 + r] = fmaf(tt, tt, nL[4 + r]); cl = fmaf(tt, tt, cl);
        }
        if (mirror) {
            // sum over the wave's 32 rows: lane>>4 groups (xor 16, 32)
            cs += __shfl_xor(cs, 16, 64);  cl += __shfl_xor(cl, 16, 64);
            cs += __shfl_xor(cs, 32, 64);  cl += __shfl_xor(cl, 32, 64);
            if (lane < 16) {
                atomicAdd(&shcS[g * 16 + lane], cs);
                atomicAdd(&shcL[g * 16 + lane], cl);
            }
        }
    };

    // 4 col-tiles, 2-deep register double buffer
    #pragma unroll
    for (int kk = 0; kk < 4; ++kk) b1[kk] = *(const f16x8*)(bb + 2048 + kk * 512);
    compute(b0, 0);
    #pragma unroll
    for (int kk = 0; kk < 4; ++kk) b0[kk] = *(const f16x8*)(bb + 2 * 2048 + kk * 512);
    compute(b1, 1);
    #pragma unroll
    for (int kk = 0; kk < 4; ++kk) b1[kk] = *(const f16x8*)(bb + 3 * 2048 + kk * 512);
    compute(b0, 2);
    compute(b1, 3);

    // row sums: reduce across the 16 column-lanes; store to unique slot rowX[Jc][row]
    const size_t jslot = (size_t)Jc * NROWS;
    #pragma unroll
    for (int s = 0; s < 2; ++s) {
        #pragma unroll
        for (int r = 0; r < 4; ++r) {
            float aa = nL[s * 4 + r], ss = nS[s * 4 + r];
            #pragma unroll
            for (int m = 1; m < 16; m <<= 1) {
                aa += __shfl_xor(aa, m, 64);
                ss += __shfl_xor(ss, m, 64);
            }
            if ((lane & 15) == 0) {
                const int row = i0 + s * 16 + (lane >> 4) * 4 + r;  // C/D row map (m89/m91)
                rowL[jslot + row] = aa;
                rowS[jslot + row] = ss;
            }
        }
    }

    // mirrored col sums: combine 4 waves via LDS, store to unique slot colX[I][col]
    if (mirror) {
        __syncthreads();
        if (threadIdx.x < 64) {
            colL[(size_t)I * NROWS + Jc * 64 + threadIdx.x] = shcL[threadIdx.x];
            colS[(size_t)I * NROWS + Jc * 64 + threadIdx.x] = shcS[threadIdx.x];
        }
    }
}

// ---- finalize: gather partials + positive-pair correction ----
__global__ void finalize_kernel(const _Float16* __restrict__ xf,
                                const float* __restrict__ rowL,
                                const float* __restrict__ rowS,
                                const float* __restrict__ colL,
                                const float* __restrict__ colS,
                                float* __restrict__ out) {
    const int i = blockIdx.x * 256 + threadIdx.x;
    const int g = i >> 4, ri = i & 15, ii = i & 7;
    const _Float16* base = xf + (size_t)g * 2048;

    // row i, elements: xf[g*2048 + kk*512 + ((h<<4)|ri)*8 + 0..7]
    f16x8 xi[16];
    #pragma unroll
    for (int kk = 0; kk < 4; ++kk) {
        #pragma unroll
        for (int h = 0; h < 4; ++h)
            xi[kk * 4 + h] = *(const f16x8*)(base + kk * 512 + ((h << 4) | ri) * 8);
    }

    float pL = 0.f, pS = 0.f, subL = 0.f, subS = 0.f;
    #pragma unroll
    for (int jj = 0; jj < 8; ++jj) {
        if (jj == ii) continue;
        const int rj = ri - ii + jj;               // same 16-row group (classes 8-aligned)
        float dot = 0.f;
        #pragma unroll
        for (int kk = 0; kk < 4; ++kk) {
            #pragma unroll
            for (int h = 0; h < 4; ++h) {
                f16x8 av = xi[kk * 4 + h];
                f16x8 bv = *(const f16x8*)(base + kk * 512 + ((h << 4) | rj) * 8);
#if HAVE_FDOT2
                #pragma unroll
                for (int u = 0; u < 4; ++u) {
                    f16x2 pa = { av[2 * u], av[2 * u + 1] };
                    f16x2 pb = { bv[2 * u], bv[2 * u + 1] };
                    dot = __builtin_amdgcn_fdot2(pa, pb, dot, false);
                }
#else
                #pragma unroll
                for (int u = 0; u < 8; ++u)
                    dot = fmaf((float)av[u], (float)bv[u], dot);
#endif
            }
        }
        float d2 = fmaf(-2.f, dot, 2.f);
        float d  = sqrtf(fmaxf(d2, 1e-12f));           // reference clamp
        float tt = __builtin_amdgcn_exp2f(-d * K20);   // exp(-20 d)
        pS += __builtin_amdgcn_exp2f(d * K20);         // exp(+20 d)
        pL = fmaf(tt, tt, pL);
        float tp = (d2 * K2 < DTHR) ? 0.f : tt;        // what pair_kernel added
        subS += tp;
        subL = fmaf(tp, tp, subL);
    }

    // gather negative-pair partials (all slots below are written by construction)
    const int I = i >> 7;
    float nLacc = 0.f, nSacc = 0.f;
    #pragma unroll 4
    for (int Jc = 2 * I; Jc < 128; ++Jc) {
        nLacc += rowL[(size_t)Jc * NROWS + i];
        nSacc += rowS[(size_t)Jc * NROWS + i];
    }
    #pragma unroll 4
    for (int b = 0; b < I; ++b) {
        nLacc += colL[(size_t)b * NROWS + i];
        nSacc += colS[(size_t)b * NROWS + i];
    }

    float nLv = nLacc - subL;
    float nSv = nSacc - subS;
    float aLr  = 1.0f - pL / (pL + nLv);
    float posL = logf(pS) - 16.0f;    // log(sum exp(20(d-0.8)))
    float negL = logf(nSv) + 22.0f;   // log(sum exp(20(1.1-d)))
    float v = aLr * (posL + negL);

    #pragma unroll
    for (int m = 32; m; m >>= 1) v += __shfl_xor(v, m, 64);
    __shared__ float partial[4];
    int wv = threadIdx.x >> 6, lane = threadIdx.x & 63;
    if (lane == 0) partial[wv] = v;
    __syncthreads();
    if (threadIdx.x == 0) {
        float s = partial[0] + partial[1] + partial[2] + partial[3];
        atomicAdd(out, s * (1.0f / NROWS));
    }
}

extern "C" void kernel_launch(void* const* d_in, const int* in_sizes, int n_in,
                              void* d_out, int out_size, void* d_ws, size_t ws_size,
                              hipStream_t stream) {
    const float* x = (const float*)d_in[0];
    float* out = (float*)d_out;

    _Float16* xf = (_Float16*)d_ws;              // 2 MB, fragment-major
    float* rowL = (float*)(xf + NROWS * DDIM);   // [128][8192] 4 MB
    float* rowS = rowL + 128 * NROWS;            // 4 MB
    float* colL = rowS + 128 * NROWS;            // [64][8192] 2 MB
    float* colS = colL + 64 * NROWS;             // 2 MB   (14 MB total << ws)

    convert_kernel<<<NROWS * DDIM / (256 * 4), 256, 0, stream>>>(x, xf, out);
    pair_kernel<<<NBLK, 256, 0, stream>>>(xf, rowL, rowS, colL, colS);
    finalize_kernel<<<NROWS / 256, 256, 0, stream>>>(xf, rowL, rowS, colL, colS, out);
}

// Round 4
// 96.616 us; speedup vs baseline: 1.1121x; 1.1121x over previous
//
#include <hip/hip_runtime.h>
#include <math.h>

#define NROWS 8192
#define DDIM  128
#define K20   28.853900817779268f        // 20 * log2(e)
#define K2    (K20 * K20)                // 832.5476
#define DTHR  8.3255f                    // 0.01 * K2 : self-pair mask (real pairs >> this)
#define NOFF  4032                       // sum_{I=0}^{62} (126 - 2I) off-diagonal blocks

typedef _Float16 f16x8 __attribute__((ext_vector_type(8)));
typedef _Float16 f16x4 __attribute__((ext_vector_type(4)));
typedef float    f32x4 __attribute__((ext_vector_type(4)));

// Fragment-major layout for mfma_f32_16x16x32_f16 (16-row groups):
//   xf[g*2048 + kk*512 + l*8 + j] = x[i = g*16 + (l&15)][k = kk*32 + (l>>4)*8 + j]
//
// ws layout (after xf):
//   rowL[128][8192], rowS[128][8192] : row-sum partials, slot = 64-col block Jc
//   colL[ 64][8192], colS[ 64][8192] : mirrored col-sum partials, slot = 128-row block I
//   posL[8192], posS[8192]           : positive-pair sums (exp(-40d), exp(+20d))
// Every slot gather reads is written by exactly one wave (no atomics, no zeroing):
//   row i (I = i>>7): nX = sum_{Jc=2I}^{127} rowX[Jc][i] + sum_{b=0}^{I-1} colX[b][i]
//   (slot 2I   <- diag kernel, full 128-col diagonal square, same-class excluded;
//    slot 2I+1 <- zeros from diag kernel; slots >=2I+2 <- off-diag pair blocks)

// ---- fp32 -> f16 frag-major transform + zero out ----
__global__ void convert_kernel(const float* __restrict__ x,
                               _Float16* __restrict__ xf,
                               float* __restrict__ out) {
    int idx = (blockIdx.x * 256 + threadIdx.x) * 4;    // flat (i,k) element index
    float4 v = *(const float4*)(x + idx);
    f16x4 h = { (_Float16)v.x, (_Float16)v.y, (_Float16)v.z, (_Float16)v.w };
    const int i = idx >> 7, k = idx & 127;             // k multiple of 4
    const int lane = (((k >> 3) & 3) << 4) | (i & 15);
    const int dst = (i >> 4) * 2048 + (k >> 5) * 512 + lane * 8 + (k & 7);
    *(f16x4*)(xf + dst) = h;
    if (blockIdx.x == 0 && threadIdx.x == 0) out[0] = 0.0f;
}

// ---- off-diagonal pair kernel (all blocks strictly above the diagonal square,
//      all mirrored). Block = 128 rows x 64 cols, 4 waves of 32 rows. B tiles
//      register-double-buffered. Col sums via plain per-wave LDS stores (cols
//      distinct per tile -> no atomics) + one combine after the barrier. ----
__global__ __launch_bounds__(256, 4) void pair_kernel(
        const _Float16* __restrict__ xf,
        float* __restrict__ rowL, float* __restrict__ rowS,
        float* __restrict__ colL, float* __restrict__ colS) {
    __shared__ float shcL[4][64], shcS[4][64];

    // decode block index: base(I) = I*(127-I), Jc = 2I+2 .. 127
    const int t = blockIdx.x;
    int I = (int)((127.0f - sqrtf(16129.0f - 4.0f * (float)t)) * 0.5f);
    while (I * (127 - I) > t) --I;
    while ((I + 1) * (126 - I) <= t) ++I;
    const int Jc = 2 * I + 2 + (t - I * (127 - I));

    const int w = threadIdx.x >> 6;
    const int lane = threadIdx.x & 63;
    const int i0 = I * 128 + w * 32;

    // A fragments resident: 2 strips x 4 k-chunks, one 1 KB coalesced load each
    const _Float16* ab = xf + (size_t)(I * 8 + w * 2) * 2048 + lane * 8;
    f16x8 a0[4], a1[4];
    #pragma unroll
    for (int kk = 0; kk < 4; ++kk) {
        a0[kk] = *(const f16x8*)(ab + kk * 512);
        a1[kk] = *(const f16x8*)(ab + 2048 + kk * 512);
    }

    float nL[8], nS[8];
    #pragma unroll
    for (int r = 0; r < 8; ++r) { nL[r] = 0.f; nS[r] = 0.f; }

    const _Float16* bb = xf + (size_t)(Jc * 4) * 2048 + lane * 8;
    f16x8 b0[4], b1[4];
    #pragma unroll
    for (int kk = 0; kk < 4; ++kk) b0[kk] = *(const f16x8*)(bb + kk * 512);

    auto compute = [&](f16x8 (&b)[4], int g) {
        f32x4 acc0 = {0.f,0.f,0.f,0.f}, acc1 = {0.f,0.f,0.f,0.f};
        #pragma unroll
        for (int kk = 0; kk < 4; ++kk) {
            acc0 = __builtin_amdgcn_mfma_f32_16x16x32_f16(a0[kk], b[kk], acc0, 0, 0, 0);
            acc1 = __builtin_amdgcn_mfma_f32_16x16x32_f16(a1[kk], b[kk], acc1, 0, 0, 0);
        }
        float cs = 0.f, cl = 0.f;
        #pragma unroll
        for (int r = 0; r < 4; ++r) {
            float d2s = fmaf(-2.0f * K2, acc0[r], 2.0f * K2);    // (20*log2e)^2 * d^2
            float ds  = __builtin_amdgcn_sqrtf(d2s);
            float tt  = __builtin_amdgcn_exp2f(-ds);             // exp(-20 d)
            tt = (d2s < DTHR) ? 0.0f : tt;
            nS[r] += tt; cs += tt;
            nL[r] = fmaf(tt, tt, nL[r]); cl = fmaf(tt, tt, cl);
        }
        #pragma unroll
        for (int r = 0; r < 4; ++r) {
            float d2s = fmaf(-2.0f * K2, acc1[r], 2.0f * K2);
            float ds  = __builtin_amdgcn_sqrtf(d2s);
            float tt  = __builtin_amdgcn_exp2f(-ds);
            tt = (d2s < DTHR) ? 0.0f : tt;
            nS[4 + r] += tt; cs += tt;
            nL[4 + r] = fmaf(tt, tt, nL[4 + r]); cl = fmaf(tt, tt, cl);
        }
        // mirrored col sums over the wave's 32 rows; cols distinct per tile
        cs += __shfl_xor(cs, 16, 64);  cl += __shfl_xor(cl, 16, 64);
        cs += __shfl_xor(cs, 32, 64);  cl += __shfl_xor(cl, 32, 64);
        if (lane < 16) { shcS[w][g * 16 + lane] = cs; shcL[w][g * 16 + lane] = cl; }
    };

    // 4 col-tiles, 2-deep register double buffer
    #pragma unroll
    for (int kk = 0; kk < 4; ++kk) b1[kk] = *(const f16x8*)(bb + 2048 + kk * 512);
    compute(b0, 0);
    #pragma unroll
    for (int kk = 0; kk < 4; ++kk) b0[kk] = *(const f16x8*)(bb + 2 * 2048 + kk * 512);
    compute(b1, 1);
    #pragma unroll
    for (int kk = 0; kk < 4; ++kk) b1[kk] = *(const f16x8*)(bb + 3 * 2048 + kk * 512);
    compute(b0, 2);
    compute(b1, 3);

    // row sums -> unique slot rowX[Jc][row]
    const size_t jslot = (size_t)Jc * NROWS;
    #pragma unroll
    for (int s = 0; s < 2; ++s) {
        #pragma unroll
        for (int r = 0; r < 4; ++r) {
            float aa = nL[s * 4 + r], ss = nS[s * 4 + r];
            #pragma unroll
            for (int m = 1; m < 16; m <<= 1) {
                aa += __shfl_xor(aa, m, 64);
                ss += __shfl_xor(ss, m, 64);
            }
            if ((lane & 15) == 0) {
                const int row = i0 + s * 16 + (lane >> 4) * 4 + r;  // C/D row map
                rowL[jslot + row] = aa;
                rowS[jslot + row] = ss;
            }
        }
    }

    // combine 4 waves' col sums -> unique slot colX[I][col]
    __syncthreads();
    if (threadIdx.x < 64) {
        const int c = threadIdx.x;
        colL[(size_t)I * NROWS + Jc * 64 + c] = shcL[0][c] + shcL[1][c] + shcL[2][c] + shcL[3][c];
        colS[(size_t)I * NROWS + Jc * 64 + c] = shcS[0][c] + shcS[1][c] + shcS[2][c] + shcS[3][c];
    }
}

// ---- diagonal-square kernel: block I covers rows x cols [I*128,+128)^2.
//      Negatives (different class) -> rowX slot 2I (slot 2I+1 zeroed);
//      positives (same 8-class, self excluded) -> posL/posS directly.
//      Same-class test is uniform per (s, lane-quarter, g): classes 8-aligned. ----
__global__ __launch_bounds__(256, 2) void diag_kernel(
        const _Float16* __restrict__ xf,
        float* __restrict__ rowL, float* __restrict__ rowS,
        float* __restrict__ posL, float* __restrict__ posS) {
    const int I = blockIdx.x;
    const int w = threadIdx.x >> 6;
    const int lane = threadIdx.x & 63;
    const int i0 = I * 128 + w * 32;
    const int rq = (lane >> 4) * 4;              // C/D row-quarter offset

    const _Float16* ab = xf + (size_t)(I * 8 + w * 2) * 2048 + lane * 8;
    f16x8 a0[4], a1[4];
    #pragma unroll
    for (int kk = 0; kk < 4; ++kk) {
        a0[kk] = *(const f16x8*)(ab + kk * 512);
        a1[kk] = *(const f16x8*)(ab + 2048 + kk * 512);
    }

    float nL[8], nS[8], qL[8], qS[8];
    #pragma unroll
    for (int r = 0; r < 8; ++r) { nL[r] = 0.f; nS[r] = 0.f; qL[r] = 0.f; qS[r] = 0.f; }

    const _Float16* bb = xf + (size_t)(I * 8) * 2048 + lane * 8;
    f16x8 b0[4], b1[4];
    #pragma unroll
    for (int kk = 0; kk < 4; ++kk) b0[kk] = *(const f16x8*)(bb + kk * 512);

    auto compute = [&](f16x8 (&b)[4], int g) {
        f32x4 acc0 = {0.f,0.f,0.f,0.f}, acc1 = {0.f,0.f,0.f,0.f};
        #pragma unroll
        for (int kk = 0; kk < 4; ++kk) {
            acc0 = __builtin_amdgcn_mfma_f32_16x16x32_f16(a0[kk], b[kk], acc0, 0, 0, 0);
            acc1 = __builtin_amdgcn_mfma_f32_16x16x32_f16(a1[kk], b[kk], acc1, 0, 0, 0);
        }
        const int col8 = (I * 128 + g * 16 + (lane & 15)) >> 3;
        #pragma unroll
        for (int s = 0; s < 2; ++s) {
            const bool same = ((i0 + s * 16 + rq) >> 3) == col8;   // uniform over r
            #pragma unroll
            for (int r = 0; r < 4; ++r) {
                float acc = s ? acc1[r] : acc0[r];
                float d2s = fmaf(-2.0f * K2, acc, 2.0f * K2);
                float ds  = __builtin_amdgcn_sqrtf(d2s);           // NaN/garbage on self
                bool  ok  = !(d2s < DTHR);                         // self-pair mask
                float tt  = ok ? __builtin_amdgcn_exp2f(-ds) : 0.f;  // exp(-20 d)
                float pe  = ok ? __builtin_amdgcn_exp2f(ds)  : 0.f;  // exp(+20 d)
                float tn  = same ? 0.f : tt;
                float tp  = same ? tt  : 0.f;
                float pp  = same ? pe  : 0.f;
                nS[s * 4 + r] += tn; nL[s * 4 + r] = fmaf(tn, tn, nL[s * 4 + r]);
                qS[s * 4 + r] += pp; qL[s * 4 + r] = fmaf(tp, tp, qL[s * 4 + r]);
            }
        }
    };

    // 8 col-tiles, 2-deep register double buffer
    for (int g = 0; g < 8; g += 2) {
        const _Float16* p1 = bb + (size_t)(g + 1) * 2048;
        #pragma unroll
        for (int kk = 0; kk < 4; ++kk) b1[kk] = *(const f16x8*)(p1 + kk * 512);
        compute(b0, g);
        const _Float16* p2 = bb + (size_t)((g + 2) & 7) * 2048;
        #pragma unroll
        for (int kk = 0; kk < 4; ++kk) b0[kk] = *(const f16x8*)(p2 + kk * 512);
        compute(b1, g + 1);
    }

    // row-reduce and store: neg -> slot 2I (2I+1 zeroed), pos -> posL/posS
    #pragma unroll
    for (int s = 0; s < 2; ++s) {
        #pragma unroll
        for (int r = 0; r < 4; ++r) {
            float a = nL[s * 4 + r], bsum = nS[s * 4 + r];
            float c = qL[s * 4 + r], d = qS[s * 4 + r];
            #pragma unroll
            for (int m = 1; m < 16; m <<= 1) {
                a += __shfl_xor(a, m, 64);  bsum += __shfl_xor(bsum, m, 64);
                c += __shfl_xor(c, m, 64);  d += __shfl_xor(d, m, 64);
            }
            if ((lane & 15) == 0) {
                const int row = i0 + s * 16 + (lane >> 4) * 4 + r;
                rowL[(size_t)(2 * I) * NROWS + row] = a;
                rowS[(size_t)(2 * I) * NROWS + row] = bsum;
                rowL[(size_t)(2 * I + 1) * NROWS + row] = 0.f;
                rowS[(size_t)(2 * I + 1) * NROWS + row] = 0.f;
                posL[row] = c;
                posS[row] = d;
            }
        }
    }
}

// ---- gather + loss: 8 threads per row, 32 rows per block -> 256 blocks ----
__global__ void gather_kernel(const float* __restrict__ rowL,
                              const float* __restrict__ rowS,
                              const float* __restrict__ colL,
                              const float* __restrict__ colS,
                              const float* __restrict__ posL,
                              const float* __restrict__ posS,
                              float* __restrict__ out) {
    const int tid = threadIdx.x;
    const int row = blockIdx.x * 32 + (tid >> 3);
    const int j = tid & 7;
    const int I = row >> 7;                       // uniform within block (32 | 128)

    float nl = 0.f, ns = 0.f;
    for (int Jc = 2 * I + j; Jc < 128; Jc += 8) {
        nl += rowL[(size_t)Jc * NROWS + row];
        ns += rowS[(size_t)Jc * NROWS + row];
    }
    for (int b = j; b < I; b += 8) {
        nl += colL[(size_t)b * NROWS + row];
        ns += colS[(size_t)b * NROWS + row];
    }
    #pragma unroll
    for (int m = 1; m < 8; m <<= 1) {
        nl += __shfl_xor(nl, m, 64);
        ns += __shfl_xor(ns, m, 64);
    }

    float v = 0.f;
    if (j == 0) {
        float pl = posL[row], ps = posS[row];
        float aLr = 1.0f - pl / (pl + nl);
        float posLoss = logf(ps) - 16.0f;         // log(sum exp(20(d-0.8)))
        float negLoss = logf(ns) + 22.0f;         // log(sum exp(20(1.1-d)))
        v = aLr * (posLoss + negLoss);
    }
    #pragma unroll
    for (int m = 1; m < 64; m <<= 1) v += __shfl_xor(v, m, 64);

    __shared__ float part[4];
    if ((tid & 63) == 0) part[tid >> 6] = v;
    __syncthreads();
    if (tid == 0)
        atomicAdd(out, (part[0] + part[1] + part[2] + part[3]) * (1.0f / NROWS));
}

extern "C" void kernel_launch(void* const* d_in, const int* in_sizes, int n_in,
                              void* d_out, int out_size, void* d_ws, size_t ws_size,
                              hipStream_t stream) {
    const float* x = (const float*)d_in[0];
    float* out = (float*)d_out;

    _Float16* xf = (_Float16*)d_ws;              // 2 MB, fragment-major
    float* rowL = (float*)(xf + NROWS * DDIM);   // [128][8192] 4 MB
    float* rowS = rowL + 128 * NROWS;            // 4 MB
    float* colL = rowS + 128 * NROWS;            // [64][8192] 2 MB
    float* colS = colL + 64 * NROWS;             // 2 MB
    float* posL = colS + 64 * NROWS;             // 32 KB
    float* posS = posL + NROWS;                  // 32 KB  (~14.1 MB total << ws)

    convert_kernel<<<NROWS * DDIM / (256 * 4), 256, 0, stream>>>(x, xf, out);
    pair_kernel<<<NOFF, 256, 0, stream>>>(xf, rowL, rowS, colL, colS);
    diag_kernel<<<64, 256, 0, stream>>>(xf, rowL, rowS, posL, posS);
    gather_kernel<<<NROWS / 32, 256, 0, stream>>>(rowL, rowS, colL, colS, posL, posS, out);
}